// Round 19
// baseline (111.134 us; speedup 1.0000x reference)
//
#include <hip/hip_runtime.h>
#include <math.h>

#define TDIM 1000
#define BDIM 32
#define VDIM 1000
#define UDIM 100
#define SDIM 201              // 2*U+1
#define EROW 104              // padded pair-row stride (102 used)
#define LN2   0.6931471805599453f
#define PIPE 16               // software-pipeline depth (t-steps of load prefetch)
// Wave max renormalized to 2^110, rescale every 8 steps (PROVEN R11-R16).
#define SCALE_EXP 110

typedef __attribute__((ext_vector_type(2))) float f32x2;
typedef __attribute__((ext_vector_type(4))) int   i32x4;

// med3(x,0,1): 1-instr clamp; NaN input sanitizes to 0.
__device__ __forceinline__ float med3c(float x) {
    return __builtin_amdgcn_fmed3f(x, 0.f, 1.f);
}

// one DPP butterfly level: v += v[xor-partner] (0-fill outside row)
template <int CTRL>
__device__ __forceinline__ float dppadd(float v) {
    int r = __builtin_amdgcn_update_dpp(
        0, __builtin_bit_cast(int, v), CTRL, 0xf, 0xf, true);
    return v + __builtin_bit_cast(float, r);
}

// ---------------------------------------------------------------------------
// Phase 1 (R16-proven, unchanged): one wave per (t,b) row. Stores PRE-MASKED,
// PRE-SANITIZED pairs + blanks in a separate compact array.
// ---------------------------------------------------------------------------
__global__ __launch_bounds__(256) void k_lsm_gather(
    const float* __restrict__ lp, const int* __restrict__ targets,
    const int* __restrict__ tlen, float* __restrict__ etab,
    float* __restrict__ blanks)
{
    const int w = threadIdx.x >> 6, l = threadIdx.x & 63;
    const int row = blockIdx.x * 4 + w;        // row = t*B + b
    const int t = row / BDIM;
    const int b = row - t * BDIM;
    const float* base = lp + (size_t)row * VDIM;
    const float4* p4 = (const float4*)base;    // 250 float4 per row

    float4 v0 = p4[l];
    float4 v1 = p4[64 + l];
    float4 v2 = p4[128 + l];
    float4 v3;
    if (l < 58) v3 = p4[192 + l];
    else        v3 = make_float4(-INFINITY, -INFINITY, -INFINITY, -INFINITY);

    float s = __expf(v0.x) + __expf(v0.y) + __expf(v0.z) + __expf(v0.w)
            + __expf(v1.x) + __expf(v1.y) + __expf(v1.z) + __expf(v1.w)
            + __expf(v2.x) + __expf(v2.y) + __expf(v2.z) + __expf(v2.w)
            + __expf(v3.x) + __expf(v3.y) + __expf(v3.z) + __expf(v3.w);
    s = dppadd<0xB1>(s);    // quad_perm xor1
    s = dppadd<0x4E>(s);    // quad_perm xor2
    s = dppadd<0x141>(s);   // row_half_mirror
    s = dppadd<0x140>(s);   // row_mirror
    s += __shfl_xor(s, 16);
    s += __shfl_xor(s, 32);

    const float inv_s = __builtin_amdgcn_rcpf(s);
    float* erow = etab + (size_t)(b * TDIM + t) * EROW;
    const int Sb = 2 * tlen[b];
    if (l < 50) {
        const int c0 = targets[b * UDIM + 2 * l];
        const int c1 = targets[b * UDIM + 2 * l + 1];
        const float mk1 = (4 * l + 1 <= Sb) ? 1.f : 0.f;
        const float mk3 = (4 * l + 3 <= Sb) ? 1.f : 0.f;
        float2 o;
        o.x = med3c(__expf(base[c0]) * inv_s) * mk1;
        o.y = med3c(__expf(base[c1]) * inv_s) * mk3;
        *(float2*)(erow + 2 * l) = o;
    } else if (l == 50) {
        *(float2*)(erow + 100) = make_float2(0.f, 0.f);  // states 201/203: masked
    } else if (l == 51) {
        blanks[b * TDIM + t] = med3c(__expf(base[0]) * inv_s);  // blank prob
    }
}

// lane l gets lane l-1's value; lane 0 gets 0.0f (additive identity).
__device__ __forceinline__ float dpp_shr1_zero(float x) {
    int r = __builtin_amdgcn_update_dpp(
        0, __builtin_bit_cast(int, x), 0x138, 0xf, 0xf, true);
    return __builtin_bit_cast(float, r);
}

// one butterfly level of a wave64 max-reduce (p >= 0, so 0-fill is identity)
template <int CTRL>
__device__ __forceinline__ float dppmax(float v) {
    int r = __builtin_amdgcn_update_dpp(
        0, __builtin_bit_cast(int, v), CTRL, 0xf, 0xf, true);
    return fmaxf(v, __builtin_bit_cast(float, r));
}

// ---------------------------------------------------------------------------
// Phase 2: per-WAVE code identical to the proven R16 kernel (single batch per
// wave, 16-deep pipeline, imm-offset buffer loads, cadence-8 rescale).
// The single knob (R18 retry): 8 waves per block -> 2 waves per SIMD -> the
// CU scheduler interleaves two independent chains, filling the ~6 cy/instr
// dependent-issue gaps that capped the solo wave (R14-R16).
// COMPILE FIX vs R18: b depends on threadIdx (wid), so the SRD words are not
// provably wave-uniform -> compiler put the SRD in VGPRs -> invalid SRSRC
// operand. readfirstlane each SRD dword to force SGPR allocation (exact:
// wid IS wave-uniform).
// ---------------------------------------------------------------------------
__global__ __launch_bounds__(512, 2) void k_alpha(
    const float* __restrict__ etab, const float* __restrict__ blanks,
    const int* __restrict__ targets, const int* __restrict__ ilen,
    const int* __restrict__ tlen, float* __restrict__ out)
{
    const int wid = threadIdx.x >> 6;          // wave id 0..7 (wave-uniform)
    const int b = blockIdx.x * 8 + wid;        // batch for this wave
    const int l = threadIdx.x & 63;            // lane 0..63
    const float* eb = etab + (size_t)b * TDIM * EROW;
    const float* blk = blanks + b * TDIM;
    const int eoff = (2 * l <= 100) ? 2 * l : 100;   // lanes>=50 -> zero pair
    const float* plane = eb + eoff;            // per-lane pair base

    f32x2 g = {0.f, 0.f};                      // skip gates (a1f, a3f)
    if (l < 50) {
        const int c0 = targets[b * UDIM + 2 * l];
        const int c1 = targets[b * UDIM + 2 * l + 1];
        g.y = (c1 != c0) ? 1.f : 0.f;
        if (l >= 1) g.x = (c0 != targets[b * UDIM + 2 * l - 1]) ? 1.f : 0.f;
    }

    const int u_b = tlen[b];
    const int Sb  = 2 * u_b;

    // t = 0 init: valid states get the 1e-30 floor (reference semantics),
    // garbage states get EXACTLY 0 (stay 0 forever)
    f32x2 pr0 = *(const f32x2*)plane;          // pre-sanitized in phase 1
    float bl0 = blk[0];
    const float F = 1e-30f * 0x1p110f;
    f32x2 E, O;
    E.x = (4 * l     <= Sb) ? F : 0.f;
    E.y = (4 * l + 2 <= Sb) ? F : 0.f;
    O.x = (4 * l + 1 <= Sb) ? F : 0.f;
    O.y = (4 * l + 3 <= Sb) ? F : 0.f;
    if (l == 0) {
        E.x = bl0   * 0x1p110f;                // s=0: blank
        O.x = pr0.x * 0x1p110f;                // s=1: first label
    }
    int ksum = -SCALE_EXP;                     // true log2 = log2(stored) + ksum

    int L = ilen[b];
    if (L > TDIM) L = TDIM;

    // SRDs -- readfirstlane each dword into SGPRs (wid is wave-uniform, so
    // this is exact; without it the compiler allocates VGPRs and the asm
    // SRSRC operand is invalid, R18's compile failure)
    const unsigned long long ebu = (unsigned long long)eb;
    i32x4 srd;                                 // pair buffer for this b
    srd.x = __builtin_amdgcn_readfirstlane((int)(ebu & 0xffffffffu));
    srd.y = __builtin_amdgcn_readfirstlane((int)((ebu >> 32) & 0xffffu));
    srd.z = __builtin_amdgcn_readfirstlane(TDIM * EROW * 4);
    srd.w = __builtin_amdgcn_readfirstlane(0x00020000);
    const unsigned long long blu = (unsigned long long)blk;
    i32x4 srdb;                                // blank buffer for this b
    srdb.x = __builtin_amdgcn_readfirstlane((int)(blu & 0xffffffffu));
    srdb.y = __builtin_amdgcn_readfirstlane((int)((blu >> 32) & 0xffffu));
    srdb.z = __builtin_amdgcn_readfirstlane(TDIM * 4);
    srdb.w = __builtin_amdgcn_readfirstlane(0x00020000);
    const int voff = eoff * 4;                 // per-lane pair byte offset
    int so  = EROW * 4;                        // pair soffset (group base)
    int sob = 4;                               // blank soffset (group base)

    // packed linear step (~9 VALU; raw loads, pre-sanitized)
#define STEP(LAB_, BLV_) {                                                       \
    const float ebv = (BLV_);                                                    \
    f32x2 ebp; ebp.x = ebv; ebp.y = ebv;                                         \
    const float pP3 = dpp_shr1_zero(O.y);                                        \
    f32x2 sk; sk.x = pP3; sk.y = O.x;                                            \
    const f32x2 T  = E + O;                                                      \
    const f32x2 ev = (E + sk) * ebp;                                             \
    const f32x2 od = (sk * g + T) * (LAB_);                                      \
    E = ev; O = od; }

    // wave-max -> renorm max to 2^SCALE_EXP via exact pow2 multiply
#define RESCALE() {                                                              \
    float pm = fmaxf(fmaxf(E.x, O.x), fmaxf(E.y, O.y));                          \
    pm = fmaxf(pm, 0x1p-10f);                                                    \
    pm = dppmax<0xB1>(pm);   /* quad_perm xor1  */                               \
    pm = dppmax<0x4E>(pm);   /* quad_perm xor2  */                               \
    pm = dppmax<0x141>(pm);  /* row_half_mirror */                               \
    pm = dppmax<0x140>(pm);  /* row_mirror      */                               \
    pm = dppmax<0x142>(pm);  /* row_bcast15    */                                \
    pm = dppmax<0x143>(pm);  /* row_bcast31    */                                \
    const int mb = __builtin_amdgcn_readlane(__builtin_bit_cast(int, pm), 63);   \
    const int ex = (mb >> 23) & 0xff;                                            \
    ksum += ex - (127 + SCALE_EXP);                                              \
    const float sc = __builtin_bit_cast(float, ((254 + SCALE_EXP) - ex) << 23);  \
    f32x2 scv; scv.x = sc; scv.y = sc;                                           \
    E = E * scv; O = O * scv; }

    // slot issue with compile-time 12-bit immediate offsets (OFFP < 4096)
#define ISS(J, OFFP, OFFB) {                                                     \
    asm volatile("buffer_load_dwordx2 %0, %1, %2, %3 offen offset:" OFFP         \
        : "=v"(lab[J]) : "v"(voff), "s"(srd), "s"(so));                          \
    asm volatile("buffer_load_dword %0, %1, %2, %3 offen offset:" OFFB           \
        : "=v"(blv[J]) : "v"(0), "s"(srdb), "s"(sob)); }

#define ISS8(G) \
    ISS((G)+0, "0",    "0");  ISS((G)+1, "416",  "4");                           \
    ISS((G)+2, "832",  "8");  ISS((G)+3, "1248", "12");                          \
    ISS((G)+4, "1664", "16"); ISS((G)+5, "2080", "20");                          \
    ISS((G)+6, "2496", "24"); ISS((G)+7, "2912", "28");

    // group of 8 slots = oldest 16 of 32 outstanding loads
#define WAITG8(J) asm volatile("s_waitcnt vmcnt(16)"                             \
    : "+v"(lab[(J)]),   "+v"(lab[(J)+1]), "+v"(lab[(J)+2]), "+v"(lab[(J)+3]),    \
      "+v"(lab[(J)+4]), "+v"(lab[(J)+5]), "+v"(lab[(J)+6]), "+v"(lab[(J)+7]),    \
      "+v"(blv[(J)]),   "+v"(blv[(J)+1]), "+v"(blv[(J)+2]), "+v"(blv[(J)+3]),    \
      "+v"(blv[(J)+4]), "+v"(blv[(J)+5]), "+v"(blv[(J)+6]), "+v"(blv[(J)+7]));

    // consume 8 steps, issue their replacement slots, then rescale
#define GROUP8(G) {                                                              \
    WAITG8(G);                                                                   \
    STEP(lab[(G)+0], blv[(G)+0]); STEP(lab[(G)+1], blv[(G)+1]);                  \
    STEP(lab[(G)+2], blv[(G)+2]); STEP(lab[(G)+3], blv[(G)+3]);                  \
    STEP(lab[(G)+4], blv[(G)+4]); STEP(lab[(G)+5], blv[(G)+5]);                  \
    STEP(lab[(G)+6], blv[(G)+6]); STEP(lab[(G)+7], blv[(G)+7]);                  \
    ISS8(G);                                                                     \
    so += 3328; sob += 32;                                                       \
    RESCALE(); }

    f32x2 lab[PIPE]; float blv[PIPE];
    // prologue: prefetch t=1..16 (two 8-groups)
    ISS8(0);  so += 3328; sob += 32;
    ISS8(8);  so += 3328; sob += 32;

    int t = 1;
    for (; t + PIPE - 1 < L; t += PIPE) {
        GROUP8(0);
        GROUP8(8);
    }
    asm volatile("s_waitcnt vmcnt(0)" ::: "memory");   // drain before tail

    // tail (<PIPE iters): plain L2-warm loads; rescale every step
    for (; t < L; ++t) {
        f32x2 lb = *(const f32x2*)(plane + (size_t)t * EROW);
        float bb = blk[t];
        STEP(lb, bb);
        RESCALE();
    }
#undef GROUP8
#undef WAITG8
#undef ISS8
#undef ISS
#undef RESCALE
#undef STEP

    // back to log2 domain; 1e-38 clamp guards a lone flushed read state
    __shared__ float A[8][256];
    A[wid][4 * l + 0] = __builtin_amdgcn_logf(fmaxf(E.x, 1e-38f));
    A[wid][4 * l + 1] = __builtin_amdgcn_logf(fmaxf(O.x, 1e-38f));
    A[wid][4 * l + 2] = __builtin_amdgcn_logf(fmaxf(E.y, 1e-38f));
    A[wid][4 * l + 3] = __builtin_amdgcn_logf(fmaxf(O.y, 1e-38f));
    __syncthreads();
    if (l == 0) {
        const float x1 = A[wid][2 * u_b - 1], x2 = A[wid][2 * u_b];
        const float mx = fmaxf(x1, x2), mn = fminf(x1, x2);
        const float lse2 = mx + __builtin_amdgcn_logf(
            1.f + __builtin_amdgcn_exp2f(mn - mx));
        out[b] = -(LN2 * (lse2 + (float)ksum));
    }
}

extern "C" void kernel_launch(void* const* d_in, const int* in_sizes, int n_in,
                              void* d_out, int out_size, void* d_ws, size_t ws_size,
                              hipStream_t stream) {
    const float* lp      = (const float*)d_in[0];   // [T,B,V] f32
    const int*   targets = (const int*)d_in[1];     // [B,U] i32
    const int*   ilen    = (const int*)d_in[2];     // [B] i32
    const int*   tlen    = (const int*)d_in[3];     // [B] i32
    float* out    = (float*)d_out;                  // [B] f32
    float* etab   = (float*)d_ws;                   // B*T*EROW*4 = 13.31 MB
    float* blanks = etab + (size_t)BDIM * TDIM * EROW;  // +128 KB

    k_lsm_gather<<<TDIM * BDIM / 4, 256, 0, stream>>>(lp, targets, tlen,
                                                      etab, blanks);
    k_alpha<<<BDIM / 8, 512, 0, stream>>>(etab, blanks, targets, ilen, tlen, out);
}

// Round 20
// 70.011 us; speedup vs baseline: 1.5874x; 1.5874x over previous
//
#include <hip/hip_runtime.h>
#include <math.h>

#define TDIM 1000
#define BDIM 32
#define VDIM 1000
#define UDIM 100
#define SDIM 201              // 2*U+1
#define EROW 104              // padded pair-row stride (102 used)
#define LN2   0.6931471805599453f
#define PIPE 16               // software-pipeline depth (t-steps of load prefetch)
// Wave max renormalized to 2^110, rescale every 8 steps (PROVEN R11-R16).
#define SCALE_EXP 110

typedef __attribute__((ext_vector_type(2))) float f32x2;
typedef __attribute__((ext_vector_type(4))) int   i32x4;

// med3(x,0,1): 1-instr clamp; NaN input sanitizes to 0.
__device__ __forceinline__ float med3c(float x) {
    return __builtin_amdgcn_fmed3f(x, 0.f, 1.f);
}

// one DPP butterfly level: v += v[xor-partner] (0-fill outside row)
template <int CTRL>
__device__ __forceinline__ float dppadd(float v) {
    int r = __builtin_amdgcn_update_dpp(
        0, __builtin_bit_cast(int, v), CTRL, 0xf, 0xf, true);
    return v + __builtin_bit_cast(float, r);
}

// ---------------------------------------------------------------------------
// Phase 1 (R16 structure): one wave per (t,b) row. Stores PRE-MASKED,
// PRE-SANITIZED pairs. CHANGE vs R16: blank prob goes into pair slot 100
// (lane-50 pair = (blank, 0)) so phase 2 broadcasts it with v_readlane and
// needs NO second load stream. The separate blanks array is gone.
// ---------------------------------------------------------------------------
__global__ __launch_bounds__(256) void k_lsm_gather(
    const float* __restrict__ lp, const int* __restrict__ targets,
    const int* __restrict__ tlen, float* __restrict__ etab)
{
    const int w = threadIdx.x >> 6, l = threadIdx.x & 63;
    const int row = blockIdx.x * 4 + w;        // row = t*B + b
    const int t = row / BDIM;
    const int b = row - t * BDIM;
    const float* base = lp + (size_t)row * VDIM;
    const float4* p4 = (const float4*)base;    // 250 float4 per row

    float4 v0 = p4[l];
    float4 v1 = p4[64 + l];
    float4 v2 = p4[128 + l];
    float4 v3;
    if (l < 58) v3 = p4[192 + l];
    else        v3 = make_float4(-INFINITY, -INFINITY, -INFINITY, -INFINITY);

    float s = __expf(v0.x) + __expf(v0.y) + __expf(v0.z) + __expf(v0.w)
            + __expf(v1.x) + __expf(v1.y) + __expf(v1.z) + __expf(v1.w)
            + __expf(v2.x) + __expf(v2.y) + __expf(v2.z) + __expf(v2.w)
            + __expf(v3.x) + __expf(v3.y) + __expf(v3.z) + __expf(v3.w);
    s = dppadd<0xB1>(s);    // quad_perm xor1
    s = dppadd<0x4E>(s);    // quad_perm xor2
    s = dppadd<0x141>(s);   // row_half_mirror
    s = dppadd<0x140>(s);   // row_mirror
    s += __shfl_xor(s, 16);
    s += __shfl_xor(s, 32);

    const float inv_s = __builtin_amdgcn_rcpf(s);
    float* erow = etab + (size_t)(b * TDIM + t) * EROW;
    const int Sb = 2 * tlen[b];
    if (l < 50) {
        const int c0 = targets[b * UDIM + 2 * l];
        const int c1 = targets[b * UDIM + 2 * l + 1];
        const float mk1 = (4 * l + 1 <= Sb) ? 1.f : 0.f;
        const float mk3 = (4 * l + 3 <= Sb) ? 1.f : 0.f;
        float2 o;
        o.x = med3c(__expf(base[c0]) * inv_s) * mk1;
        o.y = med3c(__expf(base[c1]) * inv_s) * mk3;
        *(float2*)(erow + 2 * l) = o;
    } else if (l == 50) {
        // slot 100 = blank (readlane source); slot 101 = 0 (state-201 odd pad)
        float2 o;
        o.x = med3c(__expf(base[0]) * inv_s);
        o.y = 0.f;
        *(float2*)(erow + 100) = o;
    }
}

// lane l gets lane l-1's value; lane 0 gets 0.0f (additive identity).
__device__ __forceinline__ float dpp_shr1_zero(float x) {
    int r = __builtin_amdgcn_update_dpp(
        0, __builtin_bit_cast(int, x), 0x138, 0xf, 0xf, true);
    return __builtin_bit_cast(float, r);
}

// one butterfly level of a wave64 max-reduce (p >= 0, so 0-fill is identity)
template <int CTRL>
__device__ __forceinline__ float dppmax(float v) {
    int r = __builtin_amdgcn_update_dpp(
        0, __builtin_bit_cast(int, v), CTRL, 0xf, 0xf, true);
    return fmaxf(v, __builtin_bit_cast(float, r));
}

// ---------------------------------------------------------------------------
// Phase 2 (R16 base: 1 wave/CU -- R19 measured 2 waves/SIMD strictly
// serialize on the per-CU vmem queue, so stay at 32 blocks x 64 threads).
// CHANGE vs R16: blank = v_readlane(pair.x, 50) -- deletes the blank load
// stream (8 loads + sob SALU per group, vmcnt 16->8). Garbage-state audit:
// state 201 = bounded shadow (<= ~0.06*max here), feeds only garbage states,
// rescale-exponent shifts are exactly compensated in ksum -> valid states
// BIT-IDENTICAL to R16. RESCALE uses v_max3.
// ---------------------------------------------------------------------------
__global__ __launch_bounds__(64, 1) void k_alpha(
    const float* __restrict__ etab, const int* __restrict__ targets,
    const int* __restrict__ ilen, const int* __restrict__ tlen,
    float* __restrict__ out)
{
    const int b = blockIdx.x;
    const int l = threadIdx.x;                 // 0..63
    const float* eb = etab + (size_t)b * TDIM * EROW;
    const int eoff = (2 * l <= 100) ? 2 * l : 100;   // lanes>=50 -> blank pair
    const float* plane = eb + eoff;            // per-lane pair base

    f32x2 g = {0.f, 0.f};                      // skip gates (a1f, a3f)
    if (l < 50) {
        const int c0 = targets[b * UDIM + 2 * l];
        const int c1 = targets[b * UDIM + 2 * l + 1];
        g.y = (c1 != c0) ? 1.f : 0.f;
        if (l >= 1) g.x = (c0 != targets[b * UDIM + 2 * l - 1]) ? 1.f : 0.f;
    }

    const int u_b = tlen[b];
    const int Sb  = 2 * u_b;

    // t = 0 init: valid states get the 1e-30 floor (reference semantics),
    // garbage states get EXACTLY 0 (state 201's shadow starts at 0 too:
    // lane 50's O.x uses pr0.x=blank only when it is a VALID state, which
    // it never is -- O.x at lane 50 is state 201 > 200 >= Sb)
    f32x2 pr0 = *(const f32x2*)plane;          // pre-sanitized in phase 1
    const float bl0 = __builtin_bit_cast(float,
        __builtin_amdgcn_readlane(__builtin_bit_cast(int, pr0.x), 50));
    const float F = 1e-30f * 0x1p110f;
    f32x2 E, O;
    E.x = (4 * l     <= Sb) ? F : 0.f;
    E.y = (4 * l + 2 <= Sb) ? F : 0.f;
    O.x = (4 * l + 1 <= Sb) ? F : 0.f;
    O.y = (4 * l + 3 <= Sb) ? F : 0.f;
    if (l == 0) {
        E.x = bl0   * 0x1p110f;                // s=0: blank
        O.x = pr0.x * 0x1p110f;                // s=1: first label
    }
    int ksum = -SCALE_EXP;                     // true log2 = log2(stored) + ksum

    int L = ilen[b];
    if (L > TDIM) L = TDIM;

    // SRD (bytes; OOB prefetch returns 0, never consumed)
    const unsigned long long ebu = (unsigned long long)eb;
    i32x4 srd;
    srd.x = (int)(ebu & 0xffffffffu);
    srd.y = (int)((ebu >> 32) & 0xffffu);
    srd.z = TDIM * EROW * 4;
    srd.w = 0x00020000;
    const int voff = eoff * 4;                 // per-lane pair byte offset
    int so = EROW * 4;                         // pair soffset (group base)

    // packed linear step; blank broadcast via readlane (compiler hoists the
    // 8 readlanes of a group right after WAITG8 -> hazards overlap)
#define STEP(LAB_) {                                                             \
    const float ebv = __builtin_bit_cast(float,                                  \
        __builtin_amdgcn_readlane(__builtin_bit_cast(int, (LAB_).x), 50));       \
    f32x2 ebp; ebp.x = ebv; ebp.y = ebv;                                         \
    const float pP3 = dpp_shr1_zero(O.y);                                        \
    f32x2 sk; sk.x = pP3; sk.y = O.x;                                            \
    const f32x2 T  = E + O;                                                      \
    const f32x2 ev = (E + sk) * ebp;                                             \
    const f32x2 od = (sk * g + T) * (LAB_);                                      \
    E = ev; O = od; }

    // wave-max -> renorm max to 2^SCALE_EXP via exact pow2 multiply
#define RESCALE() {                                                              \
    float pm = fmaxf(__builtin_amdgcn_fmed3f(                                    \
        fmaxf(E.x, O.x), fmaxf(E.y, O.y), INFINITY), 0x1p-10f);                  \
    pm = dppmax<0xB1>(pm);   /* quad_perm xor1  */                               \
    pm = dppmax<0x4E>(pm);   /* quad_perm xor2  */                               \
    pm = dppmax<0x141>(pm);  /* row_half_mirror */                               \
    pm = dppmax<0x140>(pm);  /* row_mirror      */                               \
    pm = dppmax<0x142>(pm);  /* row_bcast15    */                                \
    pm = dppmax<0x143>(pm);  /* row_bcast31    */                                \
    const int mb = __builtin_amdgcn_readlane(__builtin_bit_cast(int, pm), 63);   \
    const int ex = (mb >> 23) & 0xff;                                            \
    ksum += ex - (127 + SCALE_EXP);                                              \
    const float sc = __builtin_bit_cast(float, ((254 + SCALE_EXP) - ex) << 23);  \
    f32x2 scv; scv.x = sc; scv.y = sc;                                           \
    E = E * scv; O = O * scv; }

    // slot issue with compile-time 12-bit immediate offsets (OFFP < 4096)
#define ISS(J, OFFP)                                                             \
    asm volatile("buffer_load_dwordx2 %0, %1, %2, %3 offen offset:" OFFP         \
        : "=v"(lab[J]) : "v"(voff), "s"(srd), "s"(so));

#define ISS8(G) \
    ISS((G)+0, "0");    ISS((G)+1, "416");                                       \
    ISS((G)+2, "832");  ISS((G)+3, "1248");                                      \
    ISS((G)+4, "1664"); ISS((G)+5, "2080");                                      \
    ISS((G)+6, "2496"); ISS((G)+7, "2912");

    // group of 8 slots = oldest 8 of 16 outstanding loads
#define WAITG8(J) asm volatile("s_waitcnt vmcnt(8)"                              \
    : "+v"(lab[(J)]),   "+v"(lab[(J)+1]), "+v"(lab[(J)+2]), "+v"(lab[(J)+3]),    \
      "+v"(lab[(J)+4]), "+v"(lab[(J)+5]), "+v"(lab[(J)+6]), "+v"(lab[(J)+7]));

    // consume 8 steps, issue their replacement slots, then rescale
#define GROUP8(G) {                                                              \
    WAITG8(G);                                                                   \
    STEP(lab[(G)+0]); STEP(lab[(G)+1]);                                          \
    STEP(lab[(G)+2]); STEP(lab[(G)+3]);                                          \
    STEP(lab[(G)+4]); STEP(lab[(G)+5]);                                          \
    STEP(lab[(G)+6]); STEP(lab[(G)+7]);                                          \
    ISS8(G);                                                                     \
    so += 3328;                                                                  \
    RESCALE(); }

    f32x2 lab[PIPE];
    // prologue: prefetch t=1..16 (two 8-groups)
    ISS8(0);  so += 3328;
    ISS8(8);  so += 3328;

    int t = 1;
    for (; t + PIPE - 1 < L; t += PIPE) {
        GROUP8(0);
        GROUP8(8);
    }
    asm volatile("s_waitcnt vmcnt(0)" ::: "memory");   // drain before tail

    // tail (<PIPE iters): plain L2-warm loads; rescale every step
    for (; t < L; ++t) {
        f32x2 lb = *(const f32x2*)(plane + (size_t)t * EROW);
        STEP(lb);
        RESCALE();
    }
#undef GROUP8
#undef WAITG8
#undef ISS8
#undef ISS
#undef RESCALE
#undef STEP

    // back to log2 domain; 1e-38 clamp guards a lone flushed read state
    __shared__ float A[256];
    A[4 * l + 0] = __builtin_amdgcn_logf(fmaxf(E.x, 1e-38f));
    A[4 * l + 1] = __builtin_amdgcn_logf(fmaxf(O.x, 1e-38f));
    A[4 * l + 2] = __builtin_amdgcn_logf(fmaxf(E.y, 1e-38f));
    A[4 * l + 3] = __builtin_amdgcn_logf(fmaxf(O.y, 1e-38f));
    __syncthreads();
    if (l == 0) {
        const float x1 = A[2 * u_b - 1], x2 = A[2 * u_b];
        const float mx = fmaxf(x1, x2), mn = fminf(x1, x2);
        const float lse2 = mx + __builtin_amdgcn_logf(
            1.f + __builtin_amdgcn_exp2f(mn - mx));
        out[b] = -(LN2 * (lse2 + (float)ksum));
    }
}

extern "C" void kernel_launch(void* const* d_in, const int* in_sizes, int n_in,
                              void* d_out, int out_size, void* d_ws, size_t ws_size,
                              hipStream_t stream) {
    const float* lp      = (const float*)d_in[0];   // [T,B,V] f32
    const int*   targets = (const int*)d_in[1];     // [B,U] i32
    const int*   ilen    = (const int*)d_in[2];     // [B] i32
    const int*   tlen    = (const int*)d_in[3];     // [B] i32
    float* out  = (float*)d_out;                    // [B] f32
    float* etab = (float*)d_ws;                     // B*T*EROW*4 = 13.31 MB

    k_lsm_gather<<<TDIM * BDIM / 4, 256, 0, stream>>>(lp, targets, tlen, etab);
    k_alpha<<<BDIM, 64, 0, stream>>>(etab, targets, ilen, tlen, out);
}